// Round 1
// baseline (84302.643 us; speedup 1.0000x reference)
//
#include <hip/hip_runtime.h>
#include <hip/hip_bf16.h>
#include <stdint.h>

// ESN sizes (fixed by the reference)
#define NRR     4096
#define NBATCH  16
#define NFEAT   12
#define SEQLEN  1024
#define ALPHA_C 0.6f

typedef _Float16 f16x8 __attribute__((ext_vector_type(8)));
typedef float    f32x4 __attribute__((ext_vector_type(4)));

constexpr int WGS    = 256;            // one workgroup per CU; 16 A-rows each
constexpr int TPB    = 512;            // 8 waves
constexpr int WAVES  = 8;
constexpr int KCHUNK = NRR / WAVES;    // 512 K per wave
constexpr int FRAGS  = KCHUNK / 32;    // 16 MFMAs per wave per step

// Grid barrier: monotonic counter, one atomic per WG. __threadfence() gives
// agent-scope release/acquire cache ops (cross-XCD L2 visibility).
__device__ inline void gridbar(unsigned* cnt, unsigned target) {
    __threadfence();
    __syncthreads();
    if (threadIdx.x == 0) {
        __hip_atomic_fetch_add(cnt, 1u, __ATOMIC_ACQ_REL, __HIP_MEMORY_SCOPE_AGENT);
        while (__hip_atomic_load(cnt, __ATOMIC_ACQUIRE, __HIP_MEMORY_SCOPE_AGENT) < target) {
            __builtin_amdgcn_s_sleep(1);
        }
    }
    __syncthreads();
    __threadfence();
}

__global__ __launch_bounds__(TPB, 1) void esn_persistent(
    const float* __restrict__ x,    // (16, 1024, 12)
    const float* __restrict__ r0,   // (1, 16, 4096)
    const float* __restrict__ A,    // (4096, 4096) row-major
    const float* __restrict__ Bm,   // (4096, 12)
    const float* __restrict__ bias, // (4096,)
    const float* __restrict__ Cw,   // (8, 4096)
    float* __restrict__ out,        // (16, 8)
    unsigned* __restrict__ cnt,
    _Float16* __restrict__ rb0,     // (16, 4096) fp16, double buffer A
    _Float16* __restrict__ rb1,     // buffer B
    float* __restrict__ rfin)       // (16, 4096) fp32 final state
{
    const int wg    = blockIdx.x;
    const int tid   = threadIdx.x;
    const int wave  = tid >> 6;
    const int lane  = tid & 63;
    const int l15   = lane & 15;   // A-frag: row within 16-tile; B-frag: batch col
    const int g     = lane >> 4;   // k-group 0..3
    const int nbase = wg * 16;     // this WG's neuron rows [nbase, nbase+16)

    __shared__ float lds_red[WAVES][16][16]; // per-wave partial 16x16 tiles
    __shared__ float lds_x[NBATCH][NFEAT];
    __shared__ float lds_Bp[16][NFEAT];
    __shared__ float lds_bias[16];
    __shared__ float lds_out[4][128];

    // ---- Load this wave's A slice into registers as fp16 fragments ----
    // lane l of wave w holds A[nbase + (l&15)][w*512 + i*32 + (l>>4)*8 + j], j=0..7.
    // A-frag and B-frag use the same per-lane k-mapping, so any consistent
    // k-permutation inside the MFMA is sum-invariant.
    uint4 afrag[FRAGS];
    {
        const float* arow = A + (size_t)(nbase + l15) * NRR + wave * KCHUNK + g * 8;
#pragma unroll
        for (int i = 0; i < FRAGS; ++i) {
            const float4* p = (const float4*)(arow + i * 32);
            float4 f0 = p[0];
            float4 f1 = p[1];
            f16x8 h;
            h[0] = (_Float16)f0.x; h[1] = (_Float16)f0.y;
            h[2] = (_Float16)f0.z; h[3] = (_Float16)f0.w;
            h[4] = (_Float16)f1.x; h[5] = (_Float16)f1.y;
            h[6] = (_Float16)f1.z; h[7] = (_Float16)f1.w;
            afrag[i] = __builtin_bit_cast(uint4, h);
        }
    }

    if (tid < 16 * NFEAT)
        lds_Bp[tid / NFEAT][tid % NFEAT] = Bm[(size_t)(nbase + tid / NFEAT) * NFEAT + tid % NFEAT];
    if (tid < 16)
        lds_bias[tid] = bias[nbase + tid];

    // ---- master fp32 state: update thread (tid<256) owns (batch=tid>>4, n=tid&15) ----
    const int ub = tid >> 4;
    const int un = tid & 15;
    float rm = 0.0f;
    if (tid < 256) {
        rm = r0[ub * NRR + nbase + un];
        rb0[ub * NRR + nbase + un] = (_Float16)rm;
    }

    gridbar(cnt, WGS);

    const _Float16* rcur = rb0;
    _Float16*       rnxt = rb1;

    for (int t = 0; t < SEQLEN; ++t) {
        // stage x[:, t, :]
        if (tid < NBATCH * NFEAT) {
            int b = tid / NFEAT, f = tid % NFEAT;
            lds_x[b][f] = x[((size_t)b * SEQLEN + t) * NFEAT + f];
        }

        // S[n, b] = sum_k A[n,k] * r[b,k] over this wave's K-chunk
        f32x4 acc = {0.f, 0.f, 0.f, 0.f};
        const _Float16* rrow = rcur + l15 * NRR + wave * KCHUNK + g * 8;
#pragma unroll
        for (int i = 0; i < FRAGS; ++i) {
            uint4 rw = *(const uint4*)(rrow + i * 32);
            acc = __builtin_amdgcn_mfma_f32_16x16x32_f16(
                __builtin_bit_cast(f16x8, afrag[i]),
                __builtin_bit_cast(f16x8, rw),
                acc, 0, 0, 0);
        }
        // D layout (verified): col = lane&15 (batch), row = (lane>>4)*4 + j (neuron)
#pragma unroll
        for (int j = 0; j < 4; ++j)
            lds_red[wave][g * 4 + j][l15] = acc[j];
        __syncthreads();

        if (tid < 256) {
            float s = 0.f;
#pragma unroll
            for (int w = 0; w < WAVES; ++w) s += lds_red[w][un][ub];
            float p = lds_bias[un];
#pragma unroll
            for (int f = 0; f < NFEAT; ++f) p += lds_Bp[un][f] * lds_x[ub][f];
            rm = (1.0f - ALPHA_C) * rm + ALPHA_C * tanhf(s + p);
            rnxt[ub * NRR + nbase + un] = (_Float16)rm;
            if (t == SEQLEN - 1) rfin[ub * NRR + nbase + un] = rm;
        }

        gridbar(cnt, (unsigned)(t + 2) * WGS);
        _Float16* tmp = (_Float16*)rcur; rcur = rnxt; rnxt = tmp;
    }

    // ---- readout: out[b,o] = sum_k rfin[b,k] * Cw[o,k], done by WG 0 ----
    if (wg == 0) {
        const int oi   = tid & 127;  // = b*8 + o
        const int part = tid >> 7;   // 0..3, K-quarter
        const int b = oi >> 3, o = oi & 7;
        const float4* rv = (const float4*)(rfin + (size_t)b * NRR + part * (NRR / 4));
        const float4* cv = (const float4*)(Cw   + (size_t)o * NRR + part * (NRR / 4));
        float s = 0.f;
        for (int k = 0; k < NRR / 16; ++k) {
            float4 a4 = rv[k], c4 = cv[k];
            s += a4.x * c4.x + a4.y * c4.y + a4.z * c4.z + a4.w * c4.w;
        }
        lds_out[part][oi] = s;
        __syncthreads();
        if (tid < 128)
            out[tid] = lds_out[0][tid] + lds_out[1][tid] + lds_out[2][tid] + lds_out[3][tid];
    }
}

extern "C" void kernel_launch(void* const* d_in, const int* in_sizes, int n_in,
                              void* d_out, int out_size, void* d_ws, size_t ws_size,
                              hipStream_t stream) {
    const float* x   = (const float*)d_in[0];
    const float* r0  = (const float*)d_in[1];
    const float* A   = (const float*)d_in[2];
    const float* Bm  = (const float*)d_in[3];
    const float* bv  = (const float*)d_in[4];
    const float* Cw  = (const float*)d_in[5];
    float*       out = (float*)d_out;

    char* ws = (char*)d_ws;
    unsigned*  cnt  = (unsigned*)ws;                                   // [0, 1024)
    _Float16*  rb0  = (_Float16*)(ws + 1024);                          // 128 KB
    _Float16*  rb1  = (_Float16*)(ws + 1024 + NRR * NBATCH * 2);       // 128 KB
    float*     rfin = (float*)(ws + 1024 + 2 * (NRR * NBATCH * 2));    // 256 KB

    // barrier counter must start at 0 every call (graph replays included)
    hipMemsetAsync(cnt, 0, 1024, stream);

    void* args[] = {(void*)&x, (void*)&r0, (void*)&A, (void*)&Bm, (void*)&bv, (void*)&Cw,
                    (void*)&out, (void*)&cnt, (void*)&rb0, (void*)&rb1, (void*)&rfin};
    hipError_t e = hipLaunchCooperativeKernel((const void*)esn_persistent,
                                              dim3(WGS), dim3(TPB), args, 0, stream);
    if (e != hipSuccess) {
        // fallback: plain launch (grid == CU count -> co-resident in practice)
        hipLaunchKernelGGL(esn_persistent, dim3(WGS), dim3(TPB), 0, stream,
                           x, r0, A, Bm, bv, Cw, out, cnt, rb0, rb1, rfin);
    }
}

// Round 2
// 9801.495 us; speedup vs baseline: 8.6010x; 8.6010x over previous
//
#include <hip/hip_runtime.h>
#include <hip/hip_bf16.h>
#include <stdint.h>

// ESN sizes (fixed by the reference)
#define NRR     4096
#define NBATCH  16
#define NFEAT   12
#define SEQLEN  1024
#define ALPHA_C 0.6f

typedef _Float16 f16x8 __attribute__((ext_vector_type(8)));
typedef _Float16 f16x2 __attribute__((ext_vector_type(2)));
typedef float    f32x4 __attribute__((ext_vector_type(4)));

constexpr int WGS    = 256;            // one workgroup per CU; 16 A-rows each
constexpr int TPB    = 512;            // 8 waves
constexpr int WAVES  = 8;
constexpr int KCHUNK = NRR / WAVES;    // 512 K per wave
constexpr int FRAGS  = KCHUNK / 32;    // 16 MFMAs per wave per step

#define SC_AGENT __HIP_MEMORY_SCOPE_AGENT

__device__ __forceinline__ unsigned ld_rlx(const unsigned* p) {
    return __hip_atomic_load(p, __ATOMIC_RELAXED, SC_AGENT);
}
__device__ __forceinline__ void st_rlx(unsigned* p, unsigned v) {
    __hip_atomic_store(p, v, __ATOMIC_RELAXED, SC_AGENT);
}
__device__ __forceinline__ void st_rel(unsigned* p, unsigned v) {
    __hip_atomic_store(p, v, __ATOMIC_RELEASE, SC_AGENT);
}

// Contention-free grid barrier:
//  - arrival: each WG release-stores epoch into its own slot (no RMW anywhere)
//  - master (WG0 wave0): 64 lanes poll 4 slots each (relaxed), fence, then
//    write 8 replicated flags on separate 128B lines
//  - others: relaxed-poll flags[wg&7], one acquire load on exit (cache inv)
__device__ __forceinline__ void gridbar(unsigned* slots, unsigned* flags,
                                        unsigned epoch, int wg, int tid,
                                        int lane, int wave) {
    // __syncthreads drains vmcnt(0) per wave -> all write-through stores of
    // this WG are globally visible before the slot store below.
    __syncthreads();
    if (tid == 0) st_rel(&slots[wg], epoch);
    if (wg == 0) {
        if (wave == 0) {
            const int base = lane * 4;
            for (;;) {
                unsigned a = ld_rlx(&slots[base + 0]);
                unsigned b = ld_rlx(&slots[base + 1]);
                unsigned c = ld_rlx(&slots[base + 2]);
                unsigned d = ld_rlx(&slots[base + 3]);
                bool ok = (a >= epoch) & (b >= epoch) & (c >= epoch) & (d >= epoch);
                if (__all(ok)) break;
                __builtin_amdgcn_s_sleep(1);
            }
            __threadfence();  // acquire (transitivity) + release for flag stores + cache inv for WG0
            if (lane < 8) st_rel(&flags[lane * 32], epoch);
        }
    } else if (tid == 0) {
        unsigned* f = &flags[(wg & 7) * 32];
        while (ld_rlx(f) < epoch) __builtin_amdgcn_s_sleep(1);
        (void)__hip_atomic_load(f, __ATOMIC_ACQUIRE, SC_AGENT);  // invalidate L1/L2
    }
    __syncthreads();
}

__global__ __launch_bounds__(TPB, 1) void esn_persistent(
    const float* __restrict__ x,    // (16, 1024, 12)
    const float* __restrict__ r0,   // (1, 16, 4096)
    const float* __restrict__ A,    // (4096, 4096) row-major
    const float* __restrict__ Bm,   // (4096, 12)
    const float* __restrict__ bias, // (4096,)
    const float* __restrict__ Cw,   // (8, 4096)
    float* __restrict__ out,        // (16, 8)
    unsigned* __restrict__ slots,   // 256 arrival slots
    unsigned* __restrict__ flags,   // 8 release flags, 128B apart
    _Float16* __restrict__ rb0,     // (16, 4096) fp16, double buffer A
    _Float16* __restrict__ rb1,     // buffer B
    float* __restrict__ rfin)       // (16, 4096) fp32 final state
{
    const int wg    = blockIdx.x;
    const int tid   = threadIdx.x;
    const int wave  = tid >> 6;
    const int lane  = tid & 63;
    const int l15   = lane & 15;   // A-frag row within 16-tile / B-frag batch col
    const int g     = lane >> 4;   // k-group 0..3
    const int nbase = wg * 16;

    __shared__ float lds_red[WAVES][16][16];  // [w][col=batch][row=neuron] (transposed!)
    __shared__ float lds_x[2][NBATCH][NFEAT];
    __shared__ float lds_Bp[16][NFEAT];
    __shared__ float lds_bias[16];
    __shared__ float lds_out[4][128];

    // ---- A slice -> fp16 register fragments (A read exactly once) ----
    uint4 afrag[FRAGS];
    {
        const float* arow = A + (size_t)(nbase + l15) * NRR + wave * KCHUNK + g * 8;
#pragma unroll
        for (int i = 0; i < FRAGS; ++i) {
            const float4* p = (const float4*)(arow + i * 32);
            float4 f0 = p[0];
            float4 f1 = p[1];
            f16x8 h;
            h[0] = (_Float16)f0.x; h[1] = (_Float16)f0.y;
            h[2] = (_Float16)f0.z; h[3] = (_Float16)f0.w;
            h[4] = (_Float16)f1.x; h[5] = (_Float16)f1.y;
            h[6] = (_Float16)f1.z; h[7] = (_Float16)f1.w;
            afrag[i] = __builtin_bit_cast(uint4, h);
        }
    }

    // x prefetch mapping: thread tid<192 owns (batch xb, feat xf)
    const int xb = tid / NFEAT;
    const int xf = tid % NFEAT;
    const size_t xofs = (size_t)xb * SEQLEN * NFEAT + xf;

    if (tid < 16 * NFEAT)
        lds_Bp[xb][xf] = Bm[(size_t)(nbase + xb) * NFEAT + xf];
    if (tid < 16)
        lds_bias[tid] = bias[nbase + tid];
    if (tid < NBATCH * NFEAT)
        lds_x[0][xb][xf] = x[xofs];  // x[:, 0, :]

    // ---- master fp32 state: update thread tid<256 owns (batch=tid>>4, n=tid&15) ----
    const int ub = tid >> 4;
    const int un = tid & 15;
    float rm = 0.0f;
    if (tid < 256) {
        rm = r0[ub * NRR + nbase + un];
        float hi = __shfl_down(rm, 1);
        if (!(un & 1)) {
            f16x2 h2; h2[0] = (_Float16)rm; h2[1] = (_Float16)hi;
            st_rlx((unsigned*)(rb0 + (size_t)ub * NRR + nbase + un),
                   __builtin_bit_cast(unsigned, h2));
        }
    }

    gridbar(slots, flags, 1u, wg, tid, lane, wave);

    const _Float16* rcur = rb0;
    _Float16*       rnxt = rb1;

    for (int t = 0; t < SEQLEN; ++t) {
        // kick x[t+1] prefetch (latency hidden under this whole step)
        float xp = 0.0f;
        if (tid < NBATCH * NFEAT && t + 1 < SEQLEN)
            xp = x[xofs + (size_t)(t + 1) * NFEAT];

        // S[n,b] partial over this wave's K-chunk
        f32x4 acc0 = {0.f, 0.f, 0.f, 0.f};
        f32x4 acc1 = {0.f, 0.f, 0.f, 0.f};
        const _Float16* rrow = rcur + l15 * NRR + wave * KCHUNK + g * 8;
#pragma unroll
        for (int i = 0; i < FRAGS; i += 2) {
            uint4 rw0 = *(const uint4*)(rrow + i * 32);
            uint4 rw1 = *(const uint4*)(rrow + (i + 1) * 32);
            acc0 = __builtin_amdgcn_mfma_f32_16x16x32_f16(
                __builtin_bit_cast(f16x8, afrag[i]),
                __builtin_bit_cast(f16x8, rw0), acc0, 0, 0, 0);
            acc1 = __builtin_amdgcn_mfma_f32_16x16x32_f16(
                __builtin_bit_cast(f16x8, afrag[i + 1]),
                __builtin_bit_cast(f16x8, rw1), acc1, 0, 0, 0);
        }
        // D layout: col=lane&15 (batch), row=(lane>>4)*4+j (neuron).
        // Store TRANSPOSED [w][col][row] as one contiguous float4 -> conflict-free
        // write; read below is 2-way (free).
        *(f32x4*)&lds_red[wave][l15][g * 4] = acc0 + acc1;
        __syncthreads();

        if (tid < 256) {
            float s = 0.f;
#pragma unroll
            for (int w = 0; w < WAVES; ++w) s += lds_red[w][ub][un];
            float p = lds_bias[un];
            const float* xr = lds_x[t & 1][ub];
#pragma unroll
            for (int f = 0; f < NFEAT; ++f) p += lds_Bp[un][f] * xr[f];
            rm = (1.0f - ALPHA_C) * rm + ALPHA_C * tanhf(s + p);
            float hi = __shfl_down(rm, 1);
            if (!(un & 1)) {
                f16x2 h2; h2[0] = (_Float16)rm; h2[1] = (_Float16)hi;
                st_rlx((unsigned*)(rnxt + (size_t)ub * NRR + nbase + un),
                       __builtin_bit_cast(unsigned, h2));
            }
            if (t == SEQLEN - 1)
                __hip_atomic_store(&rfin[(size_t)ub * NRR + nbase + un], rm,
                                   __ATOMIC_RELAXED, SC_AGENT);
        }
        // land x prefetch into the other LDS buffer (readers are next step)
        if (tid < NBATCH * NFEAT && t + 1 < SEQLEN)
            lds_x[(t + 1) & 1][xb][xf] = xp;

        gridbar(slots, flags, (unsigned)(t + 2), wg, tid, lane, wave);
        _Float16* tmp = (_Float16*)rcur; rcur = rnxt; rnxt = tmp;
    }

    // ---- readout: out[b,o] = sum_k rfin[b,k] * Cw[o,k], by WG 0 ----
    if (wg == 0) {
        const int oi   = tid & 127;  // = b*8 + o
        const int part = tid >> 7;   // K-quarter
        const int b = oi >> 3, o = oi & 7;
        const float4* rv = (const float4*)(rfin + (size_t)b * NRR + part * (NRR / 4));
        const float4* cv = (const float4*)(Cw   + (size_t)o * NRR + part * (NRR / 4));
        float s = 0.f;
        for (int k = 0; k < NRR / 16; ++k) {
            float4 a4 = rv[k], c4 = cv[k];
            s += a4.x * c4.x + a4.y * c4.y + a4.z * c4.z + a4.w * c4.w;
        }
        lds_out[part][oi] = s;
        __syncthreads();
        if (tid < 128)
            out[tid] = lds_out[0][tid] + lds_out[1][tid] + lds_out[2][tid] + lds_out[3][tid];
    }
}

extern "C" void kernel_launch(void* const* d_in, const int* in_sizes, int n_in,
                              void* d_out, int out_size, void* d_ws, size_t ws_size,
                              hipStream_t stream) {
    const float* x   = (const float*)d_in[0];
    const float* r0  = (const float*)d_in[1];
    const float* A   = (const float*)d_in[2];
    const float* Bm  = (const float*)d_in[3];
    const float* bv  = (const float*)d_in[4];
    const float* Cw  = (const float*)d_in[5];
    float*       out = (float*)d_out;

    char* ws = (char*)d_ws;
    unsigned*  slots = (unsigned*)ws;                      // 1024 B (256 x u32)
    unsigned*  flags = (unsigned*)(ws + 1024);             // 1024 B (8 x u32 on 128B lines)
    _Float16*  rb0   = (_Float16*)(ws + 2048);             // 128 KB
    _Float16*  rb1   = (_Float16*)(ws + 2048 + NRR * NBATCH * 2);
    float*     rfin  = (float*)(ws + 2048 + 2 * (NRR * NBATCH * 2));  // 256 KB

    // slots/flags must start at 0 every call (incl. graph replays)
    hipMemsetAsync(ws, 0, 2048, stream);

    void* args[] = {(void*)&x, (void*)&r0, (void*)&A, (void*)&Bm, (void*)&bv, (void*)&Cw,
                    (void*)&out, (void*)&slots, (void*)&flags, (void*)&rb0, (void*)&rb1,
                    (void*)&rfin};
    hipError_t e = hipLaunchCooperativeKernel((const void*)esn_persistent,
                                              dim3(WGS), dim3(TPB), args, 0, stream);
    if (e != hipSuccess) {
        hipLaunchKernelGGL(esn_persistent, dim3(WGS), dim3(TPB), 0, stream,
                           x, r0, A, Bm, bv, Cw, out, slots, flags, rb0, rb1, rfin);
    }
}